// Round 6
// baseline (122.636 us; speedup 1.0000x reference)
//
#include <hip/hip_runtime.h>
#include <hip/hip_bf16.h>

#define B_ 2
#define C_ 256
#define N_ 4096
#define NH_ 8
#define HD_ 32
#define KBLK_ 64
#define SCALE_ 0.17677669529663687f
#define LOG2E_ 1.4426950408889634f

typedef __attribute__((ext_vector_type(8))) short bf16x8;
typedef __attribute__((ext_vector_type(4))) float f32x4;

__device__ inline short f2b(float f) {
    __hip_bfloat16 h = __float2bfloat16(f);
    return __builtin_bit_cast(short, h);
}

__device__ inline unsigned pk2(float a, float b) {
    unsigned r;
    asm("v_cvt_pk_bf16_f32 %0, %1, %2" : "=v"(r) : "v"(a), "v"(b));
    return r;
}

// ---------------------------------------------------------------------------
// proj_qkv: fused Q/K/V projections, LDS-free. (unchanged, passing)
// ---------------------------------------------------------------------------
__global__ __launch_bounds__(256) void proj_qkv(
    const float* __restrict__ dec, const float* __restrict__ enc,
    const float* __restrict__ Wq, const float* __restrict__ bq,
    const float* __restrict__ Wkv, const float* __restrict__ bkv,
    short* __restrict__ Qb, short* __restrict__ Kb, short* __restrict__ Vb)
{
    const int b = blockIdx.z, y = blockIdx.y;
    const int n0 = blockIdx.x * 64;
    const bool isQ = (y < 2);
    const float* In   = isQ ? dec : enc;
    const float* W    = isQ ? Wq : Wkv;
    const float* bias = isQ ? bq : bkv;
    const int row0 = isQ ? y * 128 : (y - 2) * 128;

    const int tid = threadIdx.x;
    const int w = tid >> 6, l = tid & 63, lg = l >> 4, lr = l & 15;
    const int w2 = w >> 1, w1 = w & 1;

    f32x4 acc[4][2] = {};
    const float* Inb = In + (size_t)b * C_ * N_;

    for (int c0 = 0; c0 < C_; c0 += 32) {
        bf16x8 af[4];
        #pragma unroll
        for (int db = 0; db < 4; db++) {
            const float* wp = W + (size_t)(row0 + w2 * 64 + db * 16 + lr) * C_ + c0 + lg * 8;
            float t[8];
            *(float4*)t       = *(const float4*)wp;
            *(float4*)(t + 4) = *(const float4*)(wp + 4);
            #pragma unroll
            for (int i = 0; i < 8; i++) af[db][i] = f2b(t[i]);
        }
        #pragma unroll
        for (int nb = 0; nb < 2; nb++) {
            const int n = n0 + w1 * 32 + nb * 16 + lr;
            bf16x8 bfr;
            #pragma unroll
            for (int j = 0; j < 8; j++)
                bfr[j] = f2b(Inb[(size_t)(c0 + 8 * lg + j) * N_ + n]);
            #pragma unroll
            for (int db = 0; db < 4; db++)
                acc[db][nb] = __builtin_amdgcn_mfma_f32_16x16x32_bf16(
                    af[db], bfr, acc[db][nb], 0, 0, 0);
        }
    }

    #pragma unroll
    for (int db = 0; db < 4; db++) {
        #pragma unroll
        for (int r = 0; r < 4; r++) {
            const int dl = row0 + w2 * 64 + db * 16 + lg * 4 + r;
            const float bs = bias[dl];
            #pragma unroll
            for (int nb = 0; nb < 2; nb++) {
                const int n = n0 + w1 * 32 + nb * 16 + lr;
                float v = acc[db][nb][r] + bs;
                if (y < 2) {
                    Qb[(((size_t)(b * NH_ + (dl >> 5)) * N_) + n) * HD_ + (dl & 31)]
                        = f2b(v * (SCALE_ * LOG2E_));
                } else if (y < 4) {
                    Kb[(((size_t)(b * NH_ + (dl >> 5)) * N_) + n) * HD_ + (dl & 31)]
                        = f2b(v);
                } else {
                    Vb[((size_t)(b * C_) + (dl - 256)) * N_ + n] = f2b(v);
                }
            }
        }
    }
}

// ---------------------------------------------------------------------------
// attn_kernel: 8 waves x 32 q = 256 q per block (K/V LDS frags read once,
// reused by both 16-q tiles). Softmax machinery is round-4's proven code,
// duplicated per q-tile (defer-max THR=8, per-lane lsum, epilogue shuffles).
// Staging identical to round 4 (pi-permuted K + slot swizzles, conflict-free).
// ---------------------------------------------------------------------------
__global__ __launch_bounds__(512) void attn_kernel(
    const short* __restrict__ Qb, const short* __restrict__ Kb,
    const short* __restrict__ Vb, short* __restrict__ AO)
{
    // XCD swizzle: 256 blocks = 8 XCDs x 32; 32 consecutive wg = 2 heads
    const int lin = blockIdx.x + 16 * (blockIdx.y + 8 * blockIdx.z);
    const int wg  = (lin & 7) * 32 + (lin >> 3);
    const int qblk = wg & 15, h = (wg >> 4) & 7, b = wg >> 7;

    const int tid = threadIdx.x, w = tid >> 6, l = tid & 63;
    const int lg = l >> 4, lr = l & 15;
    const int qb0 = qblk * 256 + w * 32;

    const short* Qp = Qb + ((size_t)(b * NH_ + h) * N_) * HD_;
    const short* Kp = Kb + ((size_t)(b * NH_ + h) * N_) * HD_;
    const short* Vp = Vb + ((size_t)(b * NH_ + h) * HD_) * N_;

    __shared__ short Kt[2][KBLK_][HD_];
    __shared__ short Vt[2][HD_][KBLK_];

    const int sh = tid >> 8;
    const int su = tid & 255;
    const int kkey = su >> 2, kslot = su & 3;
    const int kphys = (kslot ^ ((kkey >> 1) & 3)) * 8;
    const int ksrc = ((kkey >> 4) & 1) * 32 + ((kkey >> 2) & 3) * 8
                   + ((kkey >> 5) & 1) * 4 + (kkey & 3);
    const int vd = su >> 3, vslot = su & 7;
    const int vphys = (vslot ^ (vd & 7)) * 8;

    const int krd = (lg ^ ((lr >> 1) & 3)) * 8;

    bf16x8 qf0 = *(const bf16x8*)&Qp[(size_t)(qb0 + lr) * HD_ + lg * 8];
    bf16x8 qf1 = *(const bf16x8*)&Qp[(size_t)(qb0 + 16 + lr) * HD_ + lg * 8];

    f32x4 accA0 = {}, accA1 = {}, accB0 = {}, accB1 = {};
    float mrowA = -1e30f, lsumA = 0.0f;
    float mrowB = -1e30f, lsumB = 0.0f;

    // prologue: stage tile 0
    {
        uint4 pr = (sh == 0)
            ? *(const uint4*)(Kp + (size_t)ksrc * HD_ + kslot * 8)
            : *(const uint4*)(Vp + (size_t)vd * N_ + vslot * 8);
        if (sh == 0) *(uint4*)&Kt[0][kkey][kphys] = pr;
        else         *(uint4*)&Vt[0][vd][vphys]   = pr;
    }
    __syncthreads();

    for (int it = 0; it < N_ / KBLK_; ++it) {
        const int cur = it & 1;
        const int mnext = (it + 1) * KBLK_;
        uint4 pr;
        if (it + 1 < N_ / KBLK_) {
            pr = (sh == 0)
                ? *(const uint4*)(Kp + (size_t)(mnext + ksrc) * HD_ + kslot * 8)
                : *(const uint4*)(Vp + (size_t)vd * N_ + mnext + vslot * 8);
        }

        // ---- K frags: read once, used by both q-tiles ----
        bf16x8 kf[4];
        #pragma unroll
        for (int t = 0; t < 4; t++)
            kf[t] = *(const bf16x8*)&Kt[cur][16 * t + lr][krd];

        f32x4 z = {};
        f32x4 sA[4], sB[4];
        __builtin_amdgcn_s_setprio(1);
        #pragma unroll
        for (int t = 0; t < 4; t++)
            sA[t] = __builtin_amdgcn_mfma_f32_16x16x32_bf16(kf[t], qf0, z, 0, 0, 0);
        #pragma unroll
        for (int t = 0; t < 4; t++)
            sB[t] = __builtin_amdgcn_mfma_f32_16x16x32_bf16(kf[t], qf1, z, 0, 0, 0);
        __builtin_amdgcn_s_setprio(0);

        // ---- V frags: read once, used by both q-tiles ----
        bf16x8 vf[2][2];
        #pragma unroll
        for (int c = 0; c < 2; c++)
            #pragma unroll
            for (int hh = 0; hh < 2; hh++)
                vf[c][hh] = *(const bf16x8*)&Vt[cur][16 * hh + lr]
                                [((4 * c + lg) ^ (lr & 7)) * 8];

        // ======== q-tile A: round-4 softmax verbatim ========
        {
            float tm = sA[0][0];
            #pragma unroll
            for (int t = 0; t < 4; t++)
                #pragma unroll
                for (int r = 0; r < 4; r++) tm = fmaxf(tm, sA[t][r]);
            tm = fmaxf(tm, __shfl_xor(tm, 16));
            tm = fmaxf(tm, __shfl_xor(tm, 32));

            if (!__all(tm - mrowA <= 8.0f)) {
                float mn = fmaxf(mrowA, tm);
                float sc = __builtin_amdgcn_exp2f(mrowA - mn);
                mrowA = mn;
                lsumA *= sc;
                #pragma unroll
                for (int r = 0; r < 4; r++) { accA0[r] *= sc; accA1[r] *= sc; }
            }

            float p[4][4];
            #pragma unroll
            for (int t = 0; t < 4; t++)
                #pragma unroll
                for (int r = 0; r < 4; r++) {
                    p[t][r] = __builtin_amdgcn_exp2f(sA[t][r] - mrowA);
                    lsumA += p[t][r];
                }

            __builtin_amdgcn_s_setprio(1);
            #pragma unroll
            for (int c = 0; c < 2; c++) {
                union { bf16x8 v; unsigned u[4]; } pu;
                pu.u[0] = pk2(p[c][0], p[c][1]);
                pu.u[1] = pk2(p[c][2], p[c][3]);
                pu.u[2] = pk2(p[c + 2][0], p[c + 2][1]);
                pu.u[3] = pk2(p[c + 2][2], p[c + 2][3]);
                accA0 = __builtin_amdgcn_mfma_f32_16x16x32_bf16(vf[c][0], pu.v, accA0, 0, 0, 0);
                accA1 = __builtin_amdgcn_mfma_f32_16x16x32_bf16(vf[c][1], pu.v, accA1, 0, 0, 0);
            }
            __builtin_amdgcn_s_setprio(0);
        }

        // ======== q-tile B: same body on sB ========
        {
            float tm = sB[0][0];
            #pragma unroll
            for (int t = 0; t < 4; t++)
                #pragma unroll
                for (int r = 0; r < 4; r++) tm = fmaxf(tm, sB[t][r]);
            tm = fmaxf(tm, __shfl_xor(tm, 16));
            tm = fmaxf(tm, __shfl_xor(tm, 32));

            if (!__all(tm - mrowB <= 8.0f)) {
                float mn = fmaxf(mrowB, tm);
                float sc = __builtin_amdgcn_exp2f(mrowB - mn);
                mrowB = mn;
                lsumB *= sc;
                #pragma unroll
                for (int r = 0; r < 4; r++) { accB0[r] *= sc; accB1[r] *= sc; }
            }

            float p[4][4];
            #pragma unroll
            for (int t = 0; t < 4; t++)
                #pragma unroll
                for (int r = 0; r < 4; r++) {
                    p[t][r] = __builtin_amdgcn_exp2f(sB[t][r] - mrowB);
                    lsumB += p[t][r];
                }

            __builtin_amdgcn_s_setprio(1);
            #pragma unroll
            for (int c = 0; c < 2; c++) {
                union { bf16x8 v; unsigned u[4]; } pu;
                pu.u[0] = pk2(p[c][0], p[c][1]);
                pu.u[1] = pk2(p[c][2], p[c][3]);
                pu.u[2] = pk2(p[c + 2][0], p[c + 2][1]);
                pu.u[3] = pk2(p[c + 2][2], p[c + 2][3]);
                accB0 = __builtin_amdgcn_mfma_f32_16x16x32_bf16(vf[c][0], pu.v, accB0, 0, 0, 0);
                accB1 = __builtin_amdgcn_mfma_f32_16x16x32_bf16(vf[c][1], pu.v, accB1, 0, 0, 0);
            }
            __builtin_amdgcn_s_setprio(0);
        }

        // ---- stage tile t+1 ----
        if (it + 1 < N_ / KBLK_) {
            if (sh == 0) *(uint4*)&Kt[cur ^ 1][kkey][kphys] = pr;
            else         *(uint4*)&Vt[cur ^ 1][vd][vphys]   = pr;
        }
        __syncthreads();
    }

    lsumA += __shfl_xor(lsumA, 16);
    lsumA += __shfl_xor(lsumA, 32);
    lsumB += __shfl_xor(lsumB, 16);
    lsumB += __shfl_xor(lsumB, 32);

    {
        const float inv = 1.0f / lsumA;
        const int n = qb0 + lr;
        uint2 o;
        o.x = pk2(accA0[0] * inv, accA0[1] * inv);
        o.y = pk2(accA0[2] * inv, accA0[3] * inv);
        *(uint2*)&AO[((size_t)b * N_ + n) * C_ + h * HD_ + 4 * lg] = o;
        o.x = pk2(accA1[0] * inv, accA1[1] * inv);
        o.y = pk2(accA1[2] * inv, accA1[3] * inv);
        *(uint2*)&AO[((size_t)b * N_ + n) * C_ + h * HD_ + 16 + 4 * lg] = o;
    }
    {
        const float inv = 1.0f / lsumB;
        const int n = qb0 + 16 + lr;
        uint2 o;
        o.x = pk2(accB0[0] * inv, accB0[1] * inv);
        o.y = pk2(accB0[2] * inv, accB0[3] * inv);
        *(uint2*)&AO[((size_t)b * N_ + n) * C_ + h * HD_ + 4 * lg] = o;
        o.x = pk2(accB1[0] * inv, accB1[1] * inv);
        o.y = pk2(accB1[2] * inv, accB1[3] * inv);
        *(uint2*)&AO[((size_t)b * N_ + n) * C_ + h * HD_ + 16 + 4 * lg] = o;
    }
}

// ---------------------------------------------------------------------------
// proj_out: Out[b][d][n] = sum_c Wo[d][c] * AO[b][n][c] + bo[d]  (unchanged)
// ---------------------------------------------------------------------------
__global__ __launch_bounds__(256) void proj_out(
    const short* __restrict__ AO, const float* __restrict__ W,
    const float* __restrict__ bias, float* __restrict__ Out)
{
    const int b = blockIdx.z;
    const int n0 = blockIdx.x * 16;
    const int tid = threadIdx.x, w = tid >> 6, l = tid & 63, lg = l >> 4, lr = l & 15;

    f32x4 acc[4] = {};

    for (int c0 = 0; c0 < C_; c0 += 32) {
        bf16x8 af[4];
        #pragma unroll
        for (int db = 0; db < 4; db++) {
            const float* wp = W + (size_t)(w * 64 + db * 16 + lr) * C_ + c0 + lg * 8;
            float t[8];
            *(float4*)t       = *(const float4*)wp;
            *(float4*)(t + 4) = *(const float4*)(wp + 4);
            #pragma unroll
            for (int i = 0; i < 8; i++) af[db][i] = f2b(t[i]);
        }
        bf16x8 bfr = *(const bf16x8*)&AO[((size_t)b * N_ + n0 + lr) * C_ + c0 + lg * 8];
        #pragma unroll
        for (int db = 0; db < 4; db++)
            acc[db] = __builtin_amdgcn_mfma_f32_16x16x32_bf16(af[db], bfr, acc[db], 0, 0, 0);
    }

    #pragma unroll
    for (int db = 0; db < 4; db++) {
        #pragma unroll
        for (int r = 0; r < 4; r++) {
            const int d = w * 64 + db * 16 + lg * 4 + r;
            Out[((size_t)(b * C_) + d) * N_ + n0 + lr] = acc[db][r] + bias[d];
        }
    }
}

// ---------------------------------------------------------------------------
extern "C" void kernel_launch(void* const* d_in, const int* in_sizes, int n_in,
                              void* d_out, int out_size, void* d_ws, size_t ws_size,
                              hipStream_t stream) {
    const float* dec = (const float*)d_in[0];
    const float* enc = (const float*)d_in[1];
    const float* Wq  = (const float*)d_in[2];
    const float* bq  = (const float*)d_in[3];
    const float* Wkv = (const float*)d_in[4];
    const float* bkv = (const float*)d_in[5];
    const float* Wo  = (const float*)d_in[6];
    const float* bo  = (const float*)d_in[7];
    float* out = (float*)d_out;

    const size_t SEG = (size_t)B_ * NH_ * N_ * HD_;
    short* Qb  = (short*)d_ws;
    short* Kb  = Qb + SEG;
    short* Vb  = Kb + SEG;
    short* AOb = Vb + SEG;

    proj_qkv<<<dim3(N_ / 64, 6, B_), 256, 0, stream>>>(dec, enc, Wq, bq, Wkv, bkv,
                                                       Qb, Kb, Vb);
    attn_kernel<<<dim3(N_ / 256, NH_, B_), 512, 0, stream>>>(Qb, Kb, Vb, AOb);
    proj_out<<<dim3(N_ / 16, 1, B_), 256, 0, stream>>>(AOb, Wo, bo, out);
}